// Round 1
// baseline (466.577 us; speedup 1.0000x reference)
//
#include <hip/hip_runtime.h>
#include <math.h>

#define NEG_SLOPE 0.2f

// ---------------------------------------------------------------------------
// GEMM: C[M,256] = A[M,K] @ W[K,256], f32 vector (no fp32 MFMA on CDNA4).
// BM=64, BN=256 (full), BK=32. A staged transposed in LDS (stride 68 floats:
// 272B = 16B-aligned rows -> ds_read_b128 fragments, banks spread).
// ---------------------------------------------------------------------------
__global__ __launch_bounds__(256) void gemm_f32(
    const float* __restrict__ A, const float* __restrict__ W,
    float* __restrict__ C, int M, int K)
{
    __shared__ float As[32][68];    // [k][row], padded stride 68 (272B, 16B-aligned)
    __shared__ float Ws[32][256];   // [k][col]
    const int tid = threadIdx.x;
    const int row0 = blockIdx.x * 64;
    const int tx = tid & 63;        // col group: cols tx*4 .. tx*4+3
    const int ty = tid >> 6;        // row group: rows ty*16 .. ty*16+15

    float4 acc[16];
    #pragma unroll
    for (int r = 0; r < 16; ++r) acc[r] = make_float4(0.f, 0.f, 0.f, 0.f);

    for (int k0 = 0; k0 < K; k0 += 32) {
        // stage A tile (64 rows x 32 k) transposed
        #pragma unroll
        for (int i = 0; i < 2; ++i) {
            int f4 = tid + i * 256;           // 0..511 float4 slots
            int r  = f4 >> 3;                 // 0..63
            int kq = f4 & 7;                  // k = kq*4
            int grow = row0 + r;
            float4 v = make_float4(0.f, 0.f, 0.f, 0.f);
            if (grow < M) v = *(const float4*)(A + (size_t)grow * K + k0 + kq * 4);
            As[kq*4+0][r] = v.x; As[kq*4+1][r] = v.y;
            As[kq*4+2][r] = v.z; As[kq*4+3][r] = v.w;
        }
        // stage W tile (32 k x 256 cols)
        #pragma unroll
        for (int i = 0; i < 8; ++i) {
            int f4 = tid + i * 256;           // 0..2047
            int kk = f4 >> 6;                 // 0..31
            int nq = f4 & 63;
            *(float4*)(&Ws[kk][nq*4]) =
                *(const float4*)(W + (size_t)(k0 + kk) * 256 + nq * 4);
        }
        __syncthreads();
        #pragma unroll
        for (int k = 0; k < 32; ++k) {
            float4 w4 = *(const float4*)(&Ws[k][tx*4]);
            #pragma unroll
            for (int rr = 0; rr < 4; ++rr) {
                float4 a4 = *(const float4*)(&As[k][ty*16 + rr*4]);
                acc[rr*4+0].x += a4.x*w4.x; acc[rr*4+0].y += a4.x*w4.y;
                acc[rr*4+0].z += a4.x*w4.z; acc[rr*4+0].w += a4.x*w4.w;
                acc[rr*4+1].x += a4.y*w4.x; acc[rr*4+1].y += a4.y*w4.y;
                acc[rr*4+1].z += a4.y*w4.z; acc[rr*4+1].w += a4.y*w4.w;
                acc[rr*4+2].x += a4.z*w4.x; acc[rr*4+2].y += a4.z*w4.y;
                acc[rr*4+2].z += a4.z*w4.z; acc[rr*4+2].w += a4.z*w4.w;
                acc[rr*4+3].x += a4.w*w4.x; acc[rr*4+3].y += a4.w*w4.y;
                acc[rr*4+3].z += a4.w*w4.z; acc[rr*4+3].w += a4.w*w4.w;
            }
        }
        __syncthreads();
    }
    #pragma unroll
    for (int r = 0; r < 16; ++r) {
        int grow = row0 + ty*16 + r;
        if (grow < M) *(float4*)(C + (size_t)grow * 256 + tx*4) = acc[r];
    }
}

// ---------------------------------------------------------------------------
// Attention logits: a_s[n,h] = <h[n,h,:], att_s[h,:]>, a_d likewise.
// One thread per (n, head).
// ---------------------------------------------------------------------------
__global__ void att_kernel(const float* __restrict__ h,
                           const float* __restrict__ att_s,
                           const float* __restrict__ att_d,
                           float* __restrict__ a_s, float* __restrict__ a_d, int N)
{
    int t = blockIdx.x * 256 + threadIdx.x;
    if (t >= N * 8) return;
    int n = t >> 3, hh = t & 7;
    const float4* hp  = (const float4*)(h + (size_t)n * 256 + hh * 32);
    const float4* asp = (const float4*)(att_s + hh * 32);
    const float4* adp = (const float4*)(att_d + hh * 32);
    float ss = 0.f, dd = 0.f;
    #pragma unroll
    for (int i = 0; i < 8; ++i) {
        float4 hv = hp[i], av = asp[i], bv = adp[i];
        ss += hv.x*av.x + hv.y*av.y + hv.z*av.z + hv.w*av.w;
        dd += hv.x*bv.x + hv.y*bv.y + hv.z*bv.z + hv.w*bv.w;
    }
    a_s[t] = ss; a_d[t] = dd;
}

// ---------------------------------------------------------------------------
// CSR build: histogram -> exclusive scan -> fill (order within segment
// arbitrary; only perturbs fp-sum order at ulp level).
// ---------------------------------------------------------------------------
__global__ void hist_kernel(const int* __restrict__ dst, int* __restrict__ counts, int E)
{
    int e = blockIdx.x * 256 + threadIdx.x;
    if (e < E) atomicAdd(&counts[dst[e]], 1);
}

__global__ __launch_bounds__(1024) void scan_kernel(
    const int* __restrict__ counts, int* __restrict__ rowptr, int N)
{
    __shared__ int buf[1024];
    __shared__ int s_carry;
    int tid = threadIdx.x;
    if (tid == 0) { s_carry = 0; rowptr[0] = 0; }
    __syncthreads();
    for (int base = 0; base < N; base += 1024) {
        int i = base + tid;
        int v = (i < N) ? counts[i] : 0;
        buf[tid] = v;
        __syncthreads();
        for (int off = 1; off < 1024; off <<= 1) {
            int t = (tid >= off) ? buf[tid - off] : 0;
            __syncthreads();
            buf[tid] += t;
            __syncthreads();
        }
        int carry = s_carry;
        __syncthreads();
        if (i < N) rowptr[i + 1] = carry + buf[tid];
        if (tid == 1023) s_carry = carry + buf[1023];
        __syncthreads();
    }
}

__global__ void fill_kernel(const int* __restrict__ src, const int* __restrict__ dst,
                            const int* __restrict__ rowptr, int* __restrict__ cursor,
                            int* __restrict__ esrc, int E)
{
    int e = blockIdx.x * 256 + threadIdx.x;
    if (e >= E) return;
    int d = dst[e];
    int pos = rowptr[d] + atomicAdd(&cursor[d], 1);
    esrc[pos] = src[e];
}

// ---------------------------------------------------------------------------
// Per-node GAT aggregation. One wave per node (4 nodes per 256-thread block,
// no LDS / no block barriers -> waves fully independent).
// Lane owns channels lane*4..lane*4+3 (single head = lane>>3).
// Online softmax over 8-edge chunks: phase-A lanes map to (edge j=lane>>3,
// head hh=lane&7); per-head max/denoms held replicated, fetched via __shfl.
// LAYER==1: out[n,256] = elu(agg + b1). LAYER==2: out[n,32] = mean_h + b2.
// ---------------------------------------------------------------------------
template<int LAYER>
__global__ __launch_bounds__(256) void gat_agg(
    const float* __restrict__ h, const float* __restrict__ a_s,
    const float* __restrict__ a_d, const int* __restrict__ rowptr,
    const int* __restrict__ esrc, const float* __restrict__ bias,
    float* __restrict__ out, int N)
{
    int n = blockIdx.x * 4 + (threadIdx.x >> 6);
    if (n >= N) return;
    int lane = threadIdx.x & 63;
    int beg = rowptr[n];
    int deg = rowptr[n + 1] - beg;
    int h_mine = lane >> 3;                 // head owning this lane's channels

    if (deg == 0) {
        if (LAYER == 1) {
            #pragma unroll
            for (int q = 0; q < 4; ++q) {
                float b = bias[lane*4 + q];
                out[(size_t)n*256 + lane*4 + q] = (b > 0.f) ? b : (expf(b) - 1.f);
            }
        } else {
            if (lane < 8) {
                #pragma unroll
                for (int q = 0; q < 4; ++q)
                    out[(size_t)n*32 + lane*4 + q] = bias[lane*4 + q];
            }
        }
        return;
    }

    int hh = lane & 7;                      // phase-A head slot
    int jj = lane >> 3;                     // phase-A edge slot
    float adn = a_d[(size_t)n*8 + hh];
    float m_run = -INFINITY, d_run = 0.f;
    float4 acc = make_float4(0.f, 0.f, 0.f, 0.f);

    int nchunk = (deg + 7) >> 3;
    for (int t = 0; t < nchunk; ++t) {
        int ei = t*8 + jj;
        int s = 0;
        float v = -INFINITY;
        if (ei < deg) {
            s = esrc[beg + ei];
            float e = a_s[(size_t)s*8 + hh] + adn;
            v = (e > 0.f) ? e : NEG_SLOPE * e;
        }
        // per-head chunk max (reduce over edge slots: lanes differing in bits 3..5)
        float m_c = v;
        m_c = fmaxf(m_c, __shfl_xor(m_c, 8));
        m_c = fmaxf(m_c, __shfl_xor(m_c, 16));
        m_c = fmaxf(m_c, __shfl_xor(m_c, 32));
        float m_new = fmaxf(m_run, m_c);
        float scale = expf(m_run - m_new);  // 0 on first chunk (m_run=-inf)
        float p = expf(v - m_new);          // 0 for invalid slots
        float d_c = p;
        d_c += __shfl_xor(d_c, 8);
        d_c += __shfl_xor(d_c, 16);
        d_c += __shfl_xor(d_c, 32);
        d_run = d_run * scale + d_c;
        m_run = m_new;
        // rescale accumulator by this lane's head scale
        float sc_mine = __shfl(scale, h_mine);
        acc.x *= sc_mine; acc.y *= sc_mine; acc.z *= sc_mine; acc.w *= sc_mine;
        // aggregate chunk edges
        int cnt = min(8, deg - t*8);
        for (int j = 0; j < cnt; ++j) {
            float pj = __shfl(p, j*8 + h_mine);
            int   sj = __shfl(s, j*8);
            float4 hv = *(const float4*)(h + (size_t)sj*256 + lane*4);
            acc.x += pj*hv.x; acc.y += pj*hv.y; acc.z += pj*hv.z; acc.w += pj*hv.w;
        }
    }
    float dfin = __shfl(d_run, h_mine) + 1e-16f;
    float invd = 1.f / dfin;
    if (LAYER == 1) {
        float r[4] = {acc.x, acc.y, acc.z, acc.w};
        #pragma unroll
        for (int q = 0; q < 4; ++q) {
            float val = r[q] * invd + bias[lane*4 + q];
            out[(size_t)n*256 + lane*4 + q] = (val > 0.f) ? val : (expf(val) - 1.f);
        }
    } else {
        acc.x *= invd; acc.y *= invd; acc.z *= invd; acc.w *= invd;
        // sum over heads: lanes differing in bits 3..5 share channel-within-head
        #pragma unroll
        for (int m = 8; m <= 32; m <<= 1) {
            acc.x += __shfl_xor(acc.x, m);
            acc.y += __shfl_xor(acc.y, m);
            acc.z += __shfl_xor(acc.z, m);
            acc.w += __shfl_xor(acc.w, m);
        }
        if (lane < 8) {
            float r[4] = {acc.x, acc.y, acc.z, acc.w};
            #pragma unroll
            for (int q = 0; q < 4; ++q)
                out[(size_t)n*32 + lane*4 + q] = r[q] * 0.125f + bias[lane*4 + q];
        }
    }
}

// ---------------------------------------------------------------------------
extern "C" void kernel_launch(void* const* d_in, const int* in_sizes, int n_in,
                              void* d_out, int out_size, void* d_ws, size_t ws_size,
                              hipStream_t stream)
{
    const float* x   = (const float*)d_in[0];
    const int*   ei  = (const int*)  d_in[1];
    const float* W1  = (const float*)d_in[2];
    const float* as1 = (const float*)d_in[3];
    const float* ad1 = (const float*)d_in[4];
    const float* b1  = (const float*)d_in[5];
    const float* W2  = (const float*)d_in[6];
    const float* as2 = (const float*)d_in[7];
    const float* ad2 = (const float*)d_in[8];
    const float* b2  = (const float*)d_in[9];

    const int N = in_sizes[0] / 128;
    const int E = in_sizes[1] / 2;
    const int* srcp = ei;
    const int* dstp = ei + E;

    // workspace layout
    float* h1   = (float*)d_ws;                  // N*256 (reused as h2)
    float* out1 = h1 + (size_t)N * 256;          // N*256
    float* a_s  = out1 + (size_t)N * 256;        // N*8
    float* a_d  = a_s + (size_t)N * 8;           // N*8
    int* counts = (int*)(a_d + (size_t)N * 8);   // N
    int* cursor = counts + N;                    // N
    int* rowptr = cursor + N;                    // N+1
    int* esrc   = rowptr + (N + 1);              // E

    // CSR build (graph shared by both layers)
    hipMemsetAsync(counts, 0, (size_t)2 * N * sizeof(int), stream);
    hist_kernel<<<(E + 255) / 256, 256, 0, stream>>>(dstp, counts, E);
    scan_kernel<<<1, 1024, 0, stream>>>(counts, rowptr, N);
    fill_kernel<<<(E + 255) / 256, 256, 0, stream>>>(srcp, dstp, rowptr, cursor, esrc, E);

    // layer 1
    gemm_f32<<<(N + 63) / 64, 256, 0, stream>>>(x, W1, h1, N, 128);
    att_kernel<<<(N * 8 + 255) / 256, 256, 0, stream>>>(h1, as1, ad1, a_s, a_d, N);
    gat_agg<1><<<(N + 3) / 4, 256, 0, stream>>>(h1, a_s, a_d, rowptr, esrc, b1, out1, N);

    // layer 2 (h2 reuses h1 buffer)
    gemm_f32<<<(N + 63) / 64, 256, 0, stream>>>(out1, W2, h1, N, 256);
    att_kernel<<<(N * 8 + 255) / 256, 256, 0, stream>>>(h1, as2, ad2, a_s, a_d, N);
    gat_agg<2><<<(N + 3) / 4, 256, 0, stream>>>(h1, a_s, a_d, rowptr, esrc, b2,
                                                (float*)d_out, N);
}

// Round 2
// 340.818 us; speedup vs baseline: 1.3690x; 1.3690x over previous
//
#include <hip/hip_runtime.h>
#include <math.h>

#define NEG_SLOPE 0.2f

typedef float f32x4 __attribute__((ext_vector_type(4)));
typedef short bf16x8 __attribute__((ext_vector_type(8)));
typedef unsigned short ushortv8 __attribute__((ext_vector_type(8)));

__device__ __forceinline__ unsigned short f2bf(float f) {
    union { float f; unsigned u; } uu; uu.f = f;
    unsigned r = uu.u + 0x7FFF + ((uu.u >> 16) & 1);   // RNE, no NaN inputs
    return (unsigned short)(r >> 16);
}

// ---------------------------------------------------------------------------
// f32 -> bf16 convert (x only). 4 elems/thread.
// ---------------------------------------------------------------------------
__global__ void cvt_kernel(const float* __restrict__ in, unsigned short* __restrict__ out, int n4)
{
    int t = blockIdx.x * 256 + threadIdx.x;
    if (t >= n4) return;
    float4 v = ((const float4*)in)[t];
    ushort4 o;
    o.x = f2bf(v.x); o.y = f2bf(v.y); o.z = f2bf(v.z); o.w = f2bf(v.w);
    ((ushort4*)out)[t] = o;
}

// ---------------------------------------------------------------------------
// W[K][256] f32 -> Wt[256][K] bf16 (transpose+convert; tiny, once).
// ---------------------------------------------------------------------------
__global__ void wtr_kernel(const float* __restrict__ W, unsigned short* __restrict__ Wt, int K)
{
    int t = blockIdx.x * 256 + threadIdx.x;
    if (t >= 256 * K) return;
    int n = t / K, k = t - n * K;
    Wt[t] = f2bf(W[(size_t)k * 256 + n]);
}

// ---------------------------------------------------------------------------
// MFMA GEMM: C[M,256] = A[M,K]bf16 @ B[K,256] with Bt[256][K]bf16 (pre-transposed).
// 128x128 tile, BK=64, 256 threads = 4 waves, each wave 64x64 (4x4 frags of
// 16x16x32). LDS XOR-swizzled (byte ^= (row&7)<<4) -> conflict-free-ish
// ds_read_b128 fragments. Reg-staged (global->reg->ds_write_b128).
// C/D layout: col=lane&15, row=(lane>>4)*4+reg  [learn_hip m89].
// A/B frag: row(col)=lane&15, k=(lane>>4)*8+i (8 contiguous k).
// ---------------------------------------------------------------------------
__global__ __launch_bounds__(256) void gemm_mfma(
    const unsigned short* __restrict__ A,   // [M][K] bf16
    const unsigned short* __restrict__ Bt,  // [256][K] bf16
    float* __restrict__ C,                  // [M][256] f32
    int M, int K)
{
    __shared__ unsigned short As[128 * 64];
    __shared__ unsigned short Bs[128 * 64];
    const int tid  = threadIdx.x;
    const int lane = tid & 63;
    const int wave = tid >> 6;
    const int wr = wave >> 1, wc = wave & 1;       // wave sub-tile (64x64)
    const int row0 = blockIdx.x * 128;
    const int col0 = blockIdx.y * 128;

    f32x4 acc[4][4] = {};

    for (int k0 = 0; k0 < K; k0 += 64) {
        // ---- load tile chunks to regs (coalesced linear 16B chunks) ----
        ushortv8 va[4], vb[4];
        #pragma unroll
        for (int i = 0; i < 4; ++i) {
            int c  = i * 256 + tid;                // 0..1023
            int r  = c >> 3, cc = c & 7;           // row, 16B-chunk-in-row
            int ga = row0 + r; if (ga >= M) ga = M - 1;
            va[i] = *(const ushortv8*)(A  + (size_t)ga * K + k0 + cc * 8);
            vb[i] = *(const ushortv8*)(Bt + (size_t)(col0 + r) * K + k0 + cc * 8);
        }
        __syncthreads();   // prior compute done before LDS overwrite
        #pragma unroll
        for (int i = 0; i < 4; ++i) {
            int c  = i * 256 + tid;
            int r  = c >> 3, cc = c & 7;
            int sl = cc ^ (r & 7);                 // XOR swizzle (involution)
            *(ushortv8*)(As + r * 64 + sl * 8) = va[i];
            *(ushortv8*)(Bs + r * 64 + sl * 8) = vb[i];
        }
        __syncthreads();

        // ---- MFMA over two k-slices of 32 ----
        #pragma unroll
        for (int kk = 0; kk < 2; ++kk) {
            const int kbyte = kk * 64 + ((lane >> 4) << 4);  // 16B chunk offset in 128B row
            bf16x8 af[4], bfr[4];
            #pragma unroll
            for (int m = 0; m < 4; ++m) {
                int r = wr * 64 + m * 16 + (lane & 15);
                af[m] = *(const bf16x8*)((const char*)As + r * 128 + (kbyte ^ ((r & 7) << 4)));
            }
            #pragma unroll
            for (int n = 0; n < 4; ++n) {
                int r = wc * 64 + n * 16 + (lane & 15);
                bfr[n] = *(const bf16x8*)((const char*)Bs + r * 128 + (kbyte ^ ((r & 7) << 4)));
            }
            #pragma unroll
            for (int m = 0; m < 4; ++m)
                #pragma unroll
                for (int n = 0; n < 4; ++n)
                    acc[m][n] = __builtin_amdgcn_mfma_f32_16x16x32_bf16(
                        af[m], bfr[n], acc[m][n], 0, 0, 0);
        }
        __syncthreads();
    }

    // ---- epilogue ----
    #pragma unroll
    for (int m = 0; m < 4; ++m) {
        int rbase = row0 + wr * 64 + m * 16 + ((lane >> 4) << 2);
        #pragma unroll
        for (int j = 0; j < 4; ++j) {
            int grow = rbase + j;
            if (grow < M) {
                #pragma unroll
                for (int n = 0; n < 4; ++n)
                    C[(size_t)grow * 256 + col0 + wc * 64 + n * 16 + (lane & 15)] = acc[m][n][j];
            }
        }
    }
}

// ---------------------------------------------------------------------------
// Attention logits: a_s[n,h] = <h[n,h,:], att_s[h,:]>, a_d likewise.
// ---------------------------------------------------------------------------
__global__ void att_kernel(const float* __restrict__ h,
                           const float* __restrict__ att_s,
                           const float* __restrict__ att_d,
                           float* __restrict__ a_s, float* __restrict__ a_d, int N)
{
    int t = blockIdx.x * 256 + threadIdx.x;
    if (t >= N * 8) return;
    int n = t >> 3, hh = t & 7;
    const float4* hp  = (const float4*)(h + (size_t)n * 256 + hh * 32);
    const float4* asp = (const float4*)(att_s + hh * 32);
    const float4* adp = (const float4*)(att_d + hh * 32);
    float ss = 0.f, dd = 0.f;
    #pragma unroll
    for (int i = 0; i < 8; ++i) {
        float4 hv = hp[i], av = asp[i], bv = adp[i];
        ss += hv.x*av.x + hv.y*av.y + hv.z*av.z + hv.w*av.w;
        dd += hv.x*bv.x + hv.y*bv.y + hv.z*bv.z + hv.w*bv.w;
    }
    a_s[t] = ss; a_d[t] = dd;
}

// ---------------------------------------------------------------------------
// CSR build
// ---------------------------------------------------------------------------
__global__ void hist_kernel(const int* __restrict__ dst, int* __restrict__ counts, int E)
{
    int e = blockIdx.x * 256 + threadIdx.x;
    if (e < E) atomicAdd(&counts[dst[e]], 1);
}

// single-block chunked scan: each thread owns ceil(N/1024) contiguous elems.
__global__ __launch_bounds__(1024) void scan_kernel(
    const int* __restrict__ counts, int* __restrict__ rowptr, int N)
{
    __shared__ int wsum[16];
    int tid = threadIdx.x;
    int chunk = (N + 1023) >> 10;
    int b = tid * chunk, e = min(b + chunk, N);
    int s = 0;
    for (int i = b; i < e; ++i) s += counts[i];
    int lane = tid & 63, wid = tid >> 6;
    int v = s;
    #pragma unroll
    for (int off = 1; off < 64; off <<= 1) {
        int u = __shfl_up(v, off);
        if (lane >= off) v += u;
    }
    if (lane == 63) wsum[wid] = v;
    __syncthreads();
    if (wid == 0 && lane < 16) {
        int w = wsum[lane];
        #pragma unroll
        for (int off = 1; off < 16; off <<= 1) {
            int u = __shfl_up(w, off);
            if (lane >= off) w += u;
        }
        wsum[lane] = w;
    }
    __syncthreads();
    int wbase = (wid > 0) ? wsum[wid - 1] : 0;
    int run = wbase + v - s;                 // exclusive prefix of this chunk
    for (int i = b; i < e; ++i) { run += counts[i]; rowptr[i + 1] = run; }
    if (tid == 0) rowptr[0] = 0;
}

__global__ void fill_kernel(const int* __restrict__ src, const int* __restrict__ dst,
                            const int* __restrict__ rowptr, int* __restrict__ cursor,
                            int* __restrict__ esrc, int E)
{
    int e = blockIdx.x * 256 + threadIdx.x;
    if (e >= E) return;
    int d = dst[e];
    int pos = rowptr[d] + atomicAdd(&cursor[d], 1);
    esrc[pos] = src[e];
}

// ---------------------------------------------------------------------------
// Per-node GAT aggregation. One wave per node; lane owns 4 channels of one
// head; online softmax over 8-edge chunks via __shfl (no LDS/barriers).
// LAYER==1: writes bf16 out_b[n,256] = bf16(elu(agg+b1))  (GEMM2 input).
// LAYER==2: writes f32 out[n,32] = mean_heads + b2.
// ---------------------------------------------------------------------------
template<int LAYER>
__global__ __launch_bounds__(256) void gat_agg(
    const float* __restrict__ h, const float* __restrict__ a_s,
    const float* __restrict__ a_d, const int* __restrict__ rowptr,
    const int* __restrict__ esrc, const float* __restrict__ bias,
    float* __restrict__ out, unsigned short* __restrict__ out_b, int N)
{
    int n = blockIdx.x * 4 + (threadIdx.x >> 6);
    if (n >= N) return;
    int lane = threadIdx.x & 63;
    int beg = rowptr[n];
    int deg = rowptr[n + 1] - beg;
    int h_mine = lane >> 3;

    if (deg == 0) {
        if (LAYER == 1) {
            ushort4 o;
            float b0 = bias[lane*4+0], b1v = bias[lane*4+1], b2v = bias[lane*4+2], b3 = bias[lane*4+3];
            o.x = f2bf(b0 > 0.f ? b0 : expf(b0) - 1.f);
            o.y = f2bf(b1v > 0.f ? b1v : expf(b1v) - 1.f);
            o.z = f2bf(b2v > 0.f ? b2v : expf(b2v) - 1.f);
            o.w = f2bf(b3 > 0.f ? b3 : expf(b3) - 1.f);
            *(ushort4*)(out_b + (size_t)n*256 + lane*4) = o;
        } else {
            if (lane < 8) {
                #pragma unroll
                for (int q = 0; q < 4; ++q)
                    out[(size_t)n*32 + lane*4 + q] = bias[lane*4 + q];
            }
        }
        return;
    }

    int hh = lane & 7;
    int jj = lane >> 3;
    float adn = a_d[(size_t)n*8 + hh];
    float m_run = -INFINITY, d_run = 0.f;
    float4 acc = make_float4(0.f, 0.f, 0.f, 0.f);

    int nchunk = (deg + 7) >> 3;
    for (int t = 0; t < nchunk; ++t) {
        int ei = t*8 + jj;
        int s = 0;
        float v = -INFINITY;
        if (ei < deg) {
            s = esrc[beg + ei];
            float e = a_s[(size_t)s*8 + hh] + adn;
            v = (e > 0.f) ? e : NEG_SLOPE * e;
        }
        float m_c = v;
        m_c = fmaxf(m_c, __shfl_xor(m_c, 8));
        m_c = fmaxf(m_c, __shfl_xor(m_c, 16));
        m_c = fmaxf(m_c, __shfl_xor(m_c, 32));
        float m_new = fmaxf(m_run, m_c);
        float scale = expf(m_run - m_new);
        float p = expf(v - m_new);
        float d_c = p;
        d_c += __shfl_xor(d_c, 8);
        d_c += __shfl_xor(d_c, 16);
        d_c += __shfl_xor(d_c, 32);
        d_run = d_run * scale + d_c;
        m_run = m_new;
        float sc_mine = __shfl(scale, h_mine);
        acc.x *= sc_mine; acc.y *= sc_mine; acc.z *= sc_mine; acc.w *= sc_mine;
        int cnt = min(8, deg - t*8);
        for (int j = 0; j < cnt; ++j) {
            float pj = __shfl(p, j*8 + h_mine);
            int   sj = __shfl(s, j*8);
            float4 hv = *(const float4*)(h + (size_t)sj*256 + lane*4);
            acc.x += pj*hv.x; acc.y += pj*hv.y; acc.z += pj*hv.z; acc.w += pj*hv.w;
        }
    }
    float dfin = __shfl(d_run, h_mine) + 1e-16f;
    float invd = 1.f / dfin;
    if (LAYER == 1) {
        float r[4] = {acc.x, acc.y, acc.z, acc.w};
        ushort4 o; unsigned short* op = (unsigned short*)&o;
        #pragma unroll
        for (int q = 0; q < 4; ++q) {
            float val = r[q] * invd + bias[lane*4 + q];
            op[q] = f2bf(val > 0.f ? val : expf(val) - 1.f);
        }
        *(ushort4*)(out_b + (size_t)n*256 + lane*4) = o;
    } else {
        acc.x *= invd; acc.y *= invd; acc.z *= invd; acc.w *= invd;
        #pragma unroll
        for (int m = 8; m <= 32; m <<= 1) {
            acc.x += __shfl_xor(acc.x, m);
            acc.y += __shfl_xor(acc.y, m);
            acc.z += __shfl_xor(acc.z, m);
            acc.w += __shfl_xor(acc.w, m);
        }
        if (lane < 8) {
            float r[4] = {acc.x, acc.y, acc.z, acc.w};
            #pragma unroll
            for (int q = 0; q < 4; ++q)
                out[(size_t)n*32 + lane*4 + q] = r[q] * 0.125f + bias[lane*4 + q];
        }
    }
}

// ---------------------------------------------------------------------------
extern "C" void kernel_launch(void* const* d_in, const int* in_sizes, int n_in,
                              void* d_out, int out_size, void* d_ws, size_t ws_size,
                              hipStream_t stream)
{
    const float* x   = (const float*)d_in[0];
    const int*   ei  = (const int*)  d_in[1];
    const float* W1  = (const float*)d_in[2];
    const float* as1 = (const float*)d_in[3];
    const float* ad1 = (const float*)d_in[4];
    const float* b1  = (const float*)d_in[5];
    const float* W2  = (const float*)d_in[6];
    const float* as2 = (const float*)d_in[7];
    const float* ad2 = (const float*)d_in[8];
    const float* b2  = (const float*)d_in[9];

    const int N = in_sizes[0] / 128;
    const int E = in_sizes[1] / 2;
    const int* srcp = ei;
    const int* dstp = ei + E;

    // ---- workspace layout (bytes) ----
    char* ws = (char*)d_ws;
    float*          hbuf  = (float*)ws;                         ws += (size_t)N * 256 * 4;  // h1 / h2
    unsigned short* xb    = (unsigned short*)ws;                ws += (size_t)N * 128 * 2;
    unsigned short* out1b = (unsigned short*)ws;                ws += (size_t)N * 256 * 2;
    unsigned short* Wt1   = (unsigned short*)ws;                ws += 256 * 128 * 2;
    unsigned short* Wt2   = (unsigned short*)ws;                ws += 256 * 256 * 2;
    float*          a_s   = (float*)ws;                         ws += (size_t)N * 8 * 4;
    float*          a_d   = (float*)ws;                         ws += (size_t)N * 8 * 4;
    int*            counts= (int*)ws;                           ws += (size_t)N * 4;
    int*            cursor= (int*)ws;                           ws += (size_t)N * 4;
    int*            rowptr= (int*)ws;                           ws += (size_t)(N + 1) * 4;
    int*            esrc  = (int*)ws;

    // ---- CSR build ----
    hipMemsetAsync(counts, 0, (size_t)2 * N * sizeof(int), stream);
    hist_kernel<<<(E + 255) / 256, 256, 0, stream>>>(dstp, counts, E);
    scan_kernel<<<1, 1024, 0, stream>>>(counts, rowptr, N);
    fill_kernel<<<(E + 255) / 256, 256, 0, stream>>>(srcp, dstp, rowptr, cursor, esrc, E);

    // ---- converts ----
    cvt_kernel<<<((N * 128 / 4) + 255) / 256, 256, 0, stream>>>(x, xb, N * 128 / 4);
    wtr_kernel<<<(256 * 128 + 255) / 256, 256, 0, stream>>>(W1, Wt1, 128);
    wtr_kernel<<<(256 * 256 + 255) / 256, 256, 0, stream>>>(W2, Wt2, 256);

    const int gridM = (N + 127) / 128;

    // ---- layer 1 ----
    gemm_mfma<<<dim3(gridM, 2), 256, 0, stream>>>(xb, Wt1, hbuf, N, 128);
    att_kernel<<<(N * 8 + 255) / 256, 256, 0, stream>>>(hbuf, as1, ad1, a_s, a_d, N);
    gat_agg<1><<<(N + 3) / 4, 256, 0, stream>>>(hbuf, a_s, a_d, rowptr, esrc, b1,
                                                nullptr, out1b, N);

    // ---- layer 2 ----
    gemm_mfma<<<dim3(gridM, 2), 256, 0, stream>>>(out1b, Wt2, hbuf, N, 256);
    att_kernel<<<(N * 8 + 255) / 256, 256, 0, stream>>>(hbuf, as2, ad2, a_s, a_d, N);
    gat_agg<2><<<(N + 3) / 4, 256, 0, stream>>>(hbuf, a_s, a_d, rowptr, esrc, b2,
                                                (float*)d_out, nullptr, N);
}

// Round 3
// 241.493 us; speedup vs baseline: 1.9320x; 1.4113x over previous
//
#include <hip/hip_runtime.h>
#include <math.h>

#define NEG_SLOPE 0.2f

typedef float f32x4 __attribute__((ext_vector_type(4)));
typedef short bf16x8 __attribute__((ext_vector_type(8)));
typedef unsigned short ushortv8 __attribute__((ext_vector_type(8)));

__device__ __forceinline__ unsigned short f2bf(float f) {
    union { float f; unsigned u; } uu; uu.f = f;
    unsigned r = uu.u + 0x7FFF + ((uu.u >> 16) & 1);   // RNE, no NaN inputs
    return (unsigned short)(r >> 16);
}
__device__ __forceinline__ float bf2f(unsigned short u) {
    union { unsigned u; float f; } x; x.u = ((unsigned)u) << 16; return x.f;
}

// ---------------------------------------------------------------------------
// f32 -> bf16 convert (x only). 4 elems/thread.
// ---------------------------------------------------------------------------
__global__ void cvt_kernel(const float* __restrict__ in, unsigned short* __restrict__ out, int n4)
{
    int t = blockIdx.x * 256 + threadIdx.x;
    if (t >= n4) return;
    float4 v = ((const float4*)in)[t];
    ushort4 o;
    o.x = f2bf(v.x); o.y = f2bf(v.y); o.z = f2bf(v.z); o.w = f2bf(v.w);
    ((ushort4*)out)[t] = o;
}

// ---------------------------------------------------------------------------
// W[K][256] f32 -> Wt[256][K] bf16 (transpose+convert; tiny, once).
// ---------------------------------------------------------------------------
__global__ void wtr_kernel(const float* __restrict__ W, unsigned short* __restrict__ Wt, int K)
{
    int t = blockIdx.x * 256 + threadIdx.x;
    if (t >= 256 * K) return;
    int n = t / K, k = t - n * K;
    Wt[t] = f2bf(W[(size_t)k * 256 + n]);
}

// ---------------------------------------------------------------------------
// MFMA GEMM: C[M,256]bf16 = A[M,K]bf16 @ B[K,256] with Bt[256][K]bf16.
// 128x128 tile, BK=64, 4 waves x (64x64). XOR-swizzled LDS, reg-staged.
// C/D frag layout: col=lane&15, row=(lane>>4)*4+reg  [learn_hip m89].
// ---------------------------------------------------------------------------
__global__ __launch_bounds__(256) void gemm_mfma(
    const unsigned short* __restrict__ A,   // [M][K] bf16
    const unsigned short* __restrict__ Bt,  // [256][K] bf16
    unsigned short* __restrict__ C,         // [M][256] bf16
    int M, int K)
{
    __shared__ unsigned short As[128 * 64];
    __shared__ unsigned short Bs[128 * 64];
    const int tid  = threadIdx.x;
    const int lane = tid & 63;
    const int wave = tid >> 6;
    const int wr = wave >> 1, wc = wave & 1;
    const int row0 = blockIdx.x * 128;
    const int col0 = blockIdx.y * 128;

    f32x4 acc[4][4] = {};

    for (int k0 = 0; k0 < K; k0 += 64) {
        ushortv8 va[4], vb[4];
        #pragma unroll
        for (int i = 0; i < 4; ++i) {
            int c  = i * 256 + tid;
            int r  = c >> 3, cc = c & 7;
            int ga = row0 + r; if (ga >= M) ga = M - 1;
            va[i] = *(const ushortv8*)(A  + (size_t)ga * K + k0 + cc * 8);
            vb[i] = *(const ushortv8*)(Bt + (size_t)(col0 + r) * K + k0 + cc * 8);
        }
        __syncthreads();
        #pragma unroll
        for (int i = 0; i < 4; ++i) {
            int c  = i * 256 + tid;
            int r  = c >> 3, cc = c & 7;
            int sl = cc ^ (r & 7);
            *(ushortv8*)(As + r * 64 + sl * 8) = va[i];
            *(ushortv8*)(Bs + r * 64 + sl * 8) = vb[i];
        }
        __syncthreads();

        #pragma unroll
        for (int kk = 0; kk < 2; ++kk) {
            const int kbyte = kk * 64 + ((lane >> 4) << 4);
            bf16x8 af[4], bfr[4];
            #pragma unroll
            for (int m = 0; m < 4; ++m) {
                int r = wr * 64 + m * 16 + (lane & 15);
                af[m] = *(const bf16x8*)((const char*)As + r * 128 + (kbyte ^ ((r & 7) << 4)));
            }
            #pragma unroll
            for (int n = 0; n < 4; ++n) {
                int r = wc * 64 + n * 16 + (lane & 15);
                bfr[n] = *(const bf16x8*)((const char*)Bs + r * 128 + (kbyte ^ ((r & 7) << 4)));
            }
            #pragma unroll
            for (int m = 0; m < 4; ++m)
                #pragma unroll
                for (int n = 0; n < 4; ++n)
                    acc[m][n] = __builtin_amdgcn_mfma_f32_16x16x32_bf16(
                        af[m], bfr[n], acc[m][n], 0, 0, 0);
        }
        __syncthreads();
    }

    #pragma unroll
    for (int m = 0; m < 4; ++m) {
        int rbase = row0 + wr * 64 + m * 16 + ((lane >> 4) << 2);
        #pragma unroll
        for (int j = 0; j < 4; ++j) {
            int grow = rbase + j;
            if (grow < M) {
                #pragma unroll
                for (int n = 0; n < 4; ++n)
                    C[(size_t)grow * 256 + col0 + wc * 64 + n * 16 + (lane & 15)] =
                        f2bf(acc[m][n][j]);
            }
        }
    }
}

// ---------------------------------------------------------------------------
// Attention logits from bf16 h.
// ---------------------------------------------------------------------------
__global__ void att_kernel(const unsigned short* __restrict__ h,
                           const float* __restrict__ att_s,
                           const float* __restrict__ att_d,
                           float* __restrict__ a_s, float* __restrict__ a_d, int N)
{
    int t = blockIdx.x * 256 + threadIdx.x;
    if (t >= N * 8) return;
    int n = t >> 3, hh = t & 7;
    const ushortv8* hp = (const ushortv8*)(h + (size_t)n * 256 + hh * 32);
    const float*    ap = att_s + hh * 32;
    const float*    bp = att_d + hh * 32;
    float ss = 0.f, dd = 0.f;
    #pragma unroll
    for (int i = 0; i < 4; ++i) {
        ushortv8 hv = hp[i];
        #pragma unroll
        for (int q = 0; q < 8; ++q) {
            float f = bf2f(hv[q]);
            ss += f * ap[i*8 + q];
            dd += f * bp[i*8 + q];
        }
    }
    a_s[t] = ss; a_d[t] = dd;
}

// ---------------------------------------------------------------------------
// CSR build: histogram -> parallel 3-phase scan -> fill.
// ---------------------------------------------------------------------------
__global__ void hist_kernel(const int* __restrict__ dst, int* __restrict__ counts, int E)
{
    int e = blockIdx.x * 256 + threadIdx.x;
    if (e < E) atomicAdd(&counts[dst[e]], 1);
}

// per-block inclusive scan of 256 elems + block total
__global__ __launch_bounds__(256) void scan_blk(
    const int* __restrict__ counts, int* __restrict__ incl, int* __restrict__ bsum, int N)
{
    __shared__ int wtot[4], wexc[4];
    int t = blockIdx.x * 256 + threadIdx.x;
    int lane = threadIdx.x & 63, wid = threadIdx.x >> 6;
    int v = (t < N) ? counts[t] : 0;
    int s = v;
    #pragma unroll
    for (int off = 1; off < 64; off <<= 1) {
        int u = __shfl_up(s, off);
        if (lane >= off) s += u;
    }
    if (lane == 63) wtot[wid] = s;
    __syncthreads();
    if (threadIdx.x == 0) {
        int r = 0;
        #pragma unroll
        for (int w = 0; w < 4; ++w) { wexc[w] = r; r += wtot[w]; }
    }
    __syncthreads();
    int out = s + wexc[wid];
    if (t < N) incl[t] = out;
    if (threadIdx.x == 255) bsum[blockIdx.x] = out;
}

// single-block exclusive scan of nb (<=256) block sums
__global__ __launch_bounds__(256) void scan_top(int* __restrict__ bsum, int nb)
{
    __shared__ int wtot[4], wexc[4];
    int tid = threadIdx.x;
    int lane = tid & 63, wid = tid >> 6;
    int v = (tid < nb) ? bsum[tid] : 0;
    int s = v;
    #pragma unroll
    for (int off = 1; off < 64; off <<= 1) {
        int u = __shfl_up(s, off);
        if (lane >= off) s += u;
    }
    if (lane == 63) wtot[wid] = s;
    __syncthreads();
    if (tid == 0) {
        int r = 0;
        #pragma unroll
        for (int w = 0; w < 4; ++w) { wexc[w] = r; r += wtot[w]; }
    }
    __syncthreads();
    if (tid < nb) bsum[tid] = s + wexc[wid] - v;   // exclusive
}

__global__ void scan_add(const int* __restrict__ incl, const int* __restrict__ bsum,
                         int* __restrict__ rowptr, int N)
{
    int t = blockIdx.x * 256 + threadIdx.x;
    if (t < N) rowptr[t + 1] = incl[t] + bsum[t >> 8];
    if (t == 0) rowptr[0] = 0;
}

__global__ void fill_kernel(const int* __restrict__ src, const int* __restrict__ dst,
                            const int* __restrict__ rowptr, int* __restrict__ cursor,
                            int* __restrict__ esrc, int E)
{
    int e = blockIdx.x * 256 + threadIdx.x;
    if (e >= E) return;
    int d = dst[e];
    int pos = rowptr[d] + atomicAdd(&cursor[d], 1);
    esrc[pos] = src[e];
}

// ---------------------------------------------------------------------------
// Per-node GAT aggregation over bf16 h. One wave per node; lane owns 4
// channels of one head; online softmax over 8-edge chunks via __shfl.
// ---------------------------------------------------------------------------
template<int LAYER>
__global__ __launch_bounds__(256) void gat_agg(
    const unsigned short* __restrict__ h, const float* __restrict__ a_s,
    const float* __restrict__ a_d, const int* __restrict__ rowptr,
    const int* __restrict__ esrc, const float* __restrict__ bias,
    float* __restrict__ out, unsigned short* __restrict__ out_b, int N)
{
    int n = blockIdx.x * 4 + (threadIdx.x >> 6);
    if (n >= N) return;
    int lane = threadIdx.x & 63;
    int beg = rowptr[n];
    int deg = rowptr[n + 1] - beg;
    int h_mine = lane >> 3;

    if (deg == 0) {
        if (LAYER == 1) {
            ushort4 o;
            float c0 = bias[lane*4+0], c1 = bias[lane*4+1], c2 = bias[lane*4+2], c3 = bias[lane*4+3];
            o.x = f2bf(c0 > 0.f ? c0 : expf(c0) - 1.f);
            o.y = f2bf(c1 > 0.f ? c1 : expf(c1) - 1.f);
            o.z = f2bf(c2 > 0.f ? c2 : expf(c2) - 1.f);
            o.w = f2bf(c3 > 0.f ? c3 : expf(c3) - 1.f);
            *(ushort4*)(out_b + (size_t)n*256 + lane*4) = o;
        } else {
            if (lane < 8) {
                #pragma unroll
                for (int q = 0; q < 4; ++q)
                    out[(size_t)n*32 + lane*4 + q] = bias[lane*4 + q];
            }
        }
        return;
    }

    int hh = lane & 7;
    int jj = lane >> 3;
    float adn = a_d[(size_t)n*8 + hh];
    float m_run = -INFINITY, d_run = 0.f;
    float4 acc = make_float4(0.f, 0.f, 0.f, 0.f);

    int nchunk = (deg + 7) >> 3;
    for (int t = 0; t < nchunk; ++t) {
        int ei = t*8 + jj;
        int s = 0;
        float v = -INFINITY;
        if (ei < deg) {
            s = esrc[beg + ei];
            float e = a_s[(size_t)s*8 + hh] + adn;
            v = (e > 0.f) ? e : NEG_SLOPE * e;
        }
        float m_c = v;
        m_c = fmaxf(m_c, __shfl_xor(m_c, 8));
        m_c = fmaxf(m_c, __shfl_xor(m_c, 16));
        m_c = fmaxf(m_c, __shfl_xor(m_c, 32));
        float m_new = fmaxf(m_run, m_c);
        float scale = expf(m_run - m_new);
        float p = expf(v - m_new);
        float d_c = p;
        d_c += __shfl_xor(d_c, 8);
        d_c += __shfl_xor(d_c, 16);
        d_c += __shfl_xor(d_c, 32);
        d_run = d_run * scale + d_c;
        m_run = m_new;
        float sc_mine = __shfl(scale, h_mine);
        acc.x *= sc_mine; acc.y *= sc_mine; acc.z *= sc_mine; acc.w *= sc_mine;
        int cnt = min(8, deg - t*8);
        if (cnt == 8) {
            #pragma unroll
            for (int j = 0; j < 8; ++j) {
                float pj = __shfl(p, j*8 + h_mine);
                int   sj = __shfl(s, j*8);
                ushort4 hv = *(const ushort4*)(h + (size_t)sj*256 + lane*4);
                acc.x += pj*bf2f(hv.x); acc.y += pj*bf2f(hv.y);
                acc.z += pj*bf2f(hv.z); acc.w += pj*bf2f(hv.w);
            }
        } else {
            for (int j = 0; j < cnt; ++j) {
                float pj = __shfl(p, j*8 + h_mine);
                int   sj = __shfl(s, j*8);
                ushort4 hv = *(const ushort4*)(h + (size_t)sj*256 + lane*4);
                acc.x += pj*bf2f(hv.x); acc.y += pj*bf2f(hv.y);
                acc.z += pj*bf2f(hv.z); acc.w += pj*bf2f(hv.w);
            }
        }
    }
    float dfin = __shfl(d_run, h_mine) + 1e-16f;
    float invd = 1.f / dfin;
    if (LAYER == 1) {
        float r[4] = {acc.x, acc.y, acc.z, acc.w};
        ushort4 o; unsigned short* op = (unsigned short*)&o;
        #pragma unroll
        for (int q = 0; q < 4; ++q) {
            float val = r[q] * invd + bias[lane*4 + q];
            op[q] = f2bf(val > 0.f ? val : expf(val) - 1.f);
        }
        *(ushort4*)(out_b + (size_t)n*256 + lane*4) = o;
    } else {
        acc.x *= invd; acc.y *= invd; acc.z *= invd; acc.w *= invd;
        #pragma unroll
        for (int m = 8; m <= 32; m <<= 1) {
            acc.x += __shfl_xor(acc.x, m);
            acc.y += __shfl_xor(acc.y, m);
            acc.z += __shfl_xor(acc.z, m);
            acc.w += __shfl_xor(acc.w, m);
        }
        if (lane < 8) {
            float r[4] = {acc.x, acc.y, acc.z, acc.w};
            #pragma unroll
            for (int q = 0; q < 4; ++q)
                out[(size_t)n*32 + lane*4 + q] = r[q] * 0.125f + bias[lane*4 + q];
        }
    }
}

// ---------------------------------------------------------------------------
extern "C" void kernel_launch(void* const* d_in, const int* in_sizes, int n_in,
                              void* d_out, int out_size, void* d_ws, size_t ws_size,
                              hipStream_t stream)
{
    const float* x   = (const float*)d_in[0];
    const int*   ei  = (const int*)  d_in[1];
    const float* W1  = (const float*)d_in[2];
    const float* as1 = (const float*)d_in[3];
    const float* ad1 = (const float*)d_in[4];
    const float* b1  = (const float*)d_in[5];
    const float* W2  = (const float*)d_in[6];
    const float* as2 = (const float*)d_in[7];
    const float* ad2 = (const float*)d_in[8];
    const float* b2  = (const float*)d_in[9];

    const int N = in_sizes[0] / 128;
    const int E = in_sizes[1] / 2;
    const int* srcp = ei;
    const int* dstp = ei + E;

    // ---- workspace layout ----
    char* ws = (char*)d_ws;
    unsigned short* hb    = (unsigned short*)ws;  ws += (size_t)N * 256 * 2;  // h1/h2 bf16
    unsigned short* xb    = (unsigned short*)ws;  ws += (size_t)N * 128 * 2;
    unsigned short* out1b = (unsigned short*)ws;  ws += (size_t)N * 256 * 2;
    unsigned short* Wt1   = (unsigned short*)ws;  ws += 256 * 128 * 2;
    unsigned short* Wt2   = (unsigned short*)ws;  ws += 256 * 256 * 2;
    float*          a_s   = (float*)ws;           ws += (size_t)N * 8 * 4;
    float*          a_d   = (float*)ws;           ws += (size_t)N * 8 * 4;
    int*            counts= (int*)ws;             ws += (size_t)N * 4;
    int*            cursor= (int*)ws;             ws += (size_t)N * 4;
    int*            incl  = (int*)ws;             ws += (size_t)N * 4;
    int*            bsum  = (int*)ws;             ws += 256 * 4;
    int*            rowptr= (int*)ws;             ws += (size_t)(N + 1) * 4;
    int*            esrc  = (int*)ws;

    const int nb = (N + 255) / 256;

    // ---- CSR build ----
    hipMemsetAsync(counts, 0, (size_t)2 * N * sizeof(int), stream);
    hist_kernel<<<(E + 255) / 256, 256, 0, stream>>>(dstp, counts, E);
    scan_blk<<<nb, 256, 0, stream>>>(counts, incl, bsum, N);
    scan_top<<<1, 256, 0, stream>>>(bsum, nb);
    scan_add<<<nb, 256, 0, stream>>>(incl, bsum, rowptr, N);
    fill_kernel<<<(E + 255) / 256, 256, 0, stream>>>(srcp, dstp, rowptr, cursor, esrc, E);

    // ---- converts ----
    cvt_kernel<<<((N * 128 / 4) + 255) / 256, 256, 0, stream>>>(x, xb, N * 128 / 4);
    wtr_kernel<<<(256 * 128 + 255) / 256, 256, 0, stream>>>(W1, Wt1, 128);
    wtr_kernel<<<(256 * 256 + 255) / 256, 256, 0, stream>>>(W2, Wt2, 256);

    const int gridM = (N + 127) / 128;

    // ---- layer 1 ----
    gemm_mfma<<<dim3(gridM, 2), 256, 0, stream>>>(xb, Wt1, hb, N, 128);
    att_kernel<<<(N * 8 + 255) / 256, 256, 0, stream>>>(hb, as1, ad1, a_s, a_d, N);
    gat_agg<1><<<(N + 3) / 4, 256, 0, stream>>>(hb, a_s, a_d, rowptr, esrc, b1,
                                                nullptr, out1b, N);

    // ---- layer 2 ----
    gemm_mfma<<<dim3(gridM, 2), 256, 0, stream>>>(out1b, Wt2, hb, N, 256);
    att_kernel<<<(N * 8 + 255) / 256, 256, 0, stream>>>(hb, as2, ad2, a_s, a_d, N);
    gat_agg<2><<<(N + 3) / 4, 256, 0, stream>>>(hb, a_s, a_d, rowptr, esrc, b2,
                                                (float*)d_out, nullptr, N);
}

// Round 4
// 216.805 us; speedup vs baseline: 2.1521x; 1.1139x over previous
//
#include <hip/hip_runtime.h>
#include <math.h>

#define NEG_SLOPE 0.2f

typedef float f32x4 __attribute__((ext_vector_type(4)));
typedef short bf16x8 __attribute__((ext_vector_type(8)));
typedef unsigned short ushortv8 __attribute__((ext_vector_type(8)));

__device__ __forceinline__ unsigned short f2bf(float f) {
    union { float f; unsigned u; } uu; uu.f = f;
    unsigned r = uu.u + 0x7FFF + ((uu.u >> 16) & 1);   // RNE, no NaN inputs
    return (unsigned short)(r >> 16);
}
__device__ __forceinline__ float bf2f(unsigned short u) {
    union { unsigned u; float f; } x; x.u = ((unsigned)u) << 16; return x.f;
}

// ---------------------------------------------------------------------------
// prep: x->bf16 convert | W1 transpose | W2 transpose | dst histogram.
// One kernel to cut launch count (graph nodes serialize on one stream).
// ---------------------------------------------------------------------------
__global__ void prep_kernel(const float* __restrict__ x, unsigned short* __restrict__ xb,
                            const float* __restrict__ W1, unsigned short* __restrict__ Wt1,
                            const float* __restrict__ W2, unsigned short* __restrict__ Wt2,
                            const int* __restrict__ dst, int* __restrict__ counts,
                            int n4x, int E)
{
    int t = blockIdx.x * 256 + threadIdx.x;
    if (t < n4x) {
        float4 v = ((const float4*)x)[t];
        ushort4 o;
        o.x = f2bf(v.x); o.y = f2bf(v.y); o.z = f2bf(v.z); o.w = f2bf(v.w);
        ((ushort4*)xb)[t] = o;
        return;
    }
    int u = t - n4x;
    if (u < 32768) {                       // Wt1[256][128]
        int nn = u >> 7, k = u & 127;
        Wt1[u] = f2bf(W1[(size_t)k * 256 + nn]);
        return;
    }
    u -= 32768;
    if (u < 65536) {                       // Wt2[256][256]
        int nn = u >> 8, k = u & 255;
        Wt2[u] = f2bf(W2[(size_t)k * 256 + nn]);
        return;
    }
    u -= 65536;
    if (u < E) atomicAdd(&counts[dst[u]], 1);
}

// ---------------------------------------------------------------------------
// MFMA GEMM: C[M,256]bf16 = A[M,K]bf16 @ Bt[256][K]bf16. 128x128 tile, BK=64,
// 4 waves x (64x64). XOR-swizzled LDS, reg-staged.
// ---------------------------------------------------------------------------
__global__ __launch_bounds__(256) void gemm_mfma(
    const unsigned short* __restrict__ A,
    const unsigned short* __restrict__ Bt,
    unsigned short* __restrict__ C,
    int M, int K)
{
    __shared__ unsigned short As[128 * 64];
    __shared__ unsigned short Bs[128 * 64];
    const int tid  = threadIdx.x;
    const int lane = tid & 63;
    const int wave = tid >> 6;
    const int wr = wave >> 1, wc = wave & 1;
    const int row0 = blockIdx.x * 128;
    const int col0 = blockIdx.y * 128;

    f32x4 acc[4][4] = {};

    for (int k0 = 0; k0 < K; k0 += 64) {
        ushortv8 va[4], vb[4];
        #pragma unroll
        for (int i = 0; i < 4; ++i) {
            int c  = i * 256 + tid;
            int r  = c >> 3, cc = c & 7;
            int ga = row0 + r; if (ga >= M) ga = M - 1;
            va[i] = *(const ushortv8*)(A  + (size_t)ga * K + k0 + cc * 8);
            vb[i] = *(const ushortv8*)(Bt + (size_t)(col0 + r) * K + k0 + cc * 8);
        }
        __syncthreads();
        #pragma unroll
        for (int i = 0; i < 4; ++i) {
            int c  = i * 256 + tid;
            int r  = c >> 3, cc = c & 7;
            int sl = cc ^ (r & 7);
            *(ushortv8*)(As + r * 64 + sl * 8) = va[i];
            *(ushortv8*)(Bs + r * 64 + sl * 8) = vb[i];
        }
        __syncthreads();

        #pragma unroll
        for (int kk = 0; kk < 2; ++kk) {
            const int kbyte = kk * 64 + ((lane >> 4) << 4);
            bf16x8 af[4], bfr[4];
            #pragma unroll
            for (int m = 0; m < 4; ++m) {
                int r = wr * 64 + m * 16 + (lane & 15);
                af[m] = *(const bf16x8*)((const char*)As + r * 128 + (kbyte ^ ((r & 7) << 4)));
            }
            #pragma unroll
            for (int n = 0; n < 4; ++n) {
                int r = wc * 64 + n * 16 + (lane & 15);
                bfr[n] = *(const bf16x8*)((const char*)Bs + r * 128 + (kbyte ^ ((r & 7) << 4)));
            }
            #pragma unroll
            for (int m = 0; m < 4; ++m)
                #pragma unroll
                for (int n = 0; n < 4; ++n)
                    acc[m][n] = __builtin_amdgcn_mfma_f32_16x16x32_bf16(
                        af[m], bfr[n], acc[m][n], 0, 0, 0);
        }
        __syncthreads();
    }

    #pragma unroll
    for (int m = 0; m < 4; ++m) {
        int rbase = row0 + wr * 64 + m * 16 + ((lane >> 4) << 2);
        #pragma unroll
        for (int j = 0; j < 4; ++j) {
            int grow = rbase + j;
            if (grow < M) {
                #pragma unroll
                for (int n = 0; n < 4; ++n)
                    C[(size_t)grow * 256 + col0 + wc * 64 + n * 16 + (lane & 15)] =
                        f2bf(acc[m][n][j]);
            }
        }
    }
}

// ---------------------------------------------------------------------------
// Attention logits from bf16 h.
// ---------------------------------------------------------------------------
__global__ void att_kernel(const unsigned short* __restrict__ h,
                           const float* __restrict__ att_s,
                           const float* __restrict__ att_d,
                           float* __restrict__ a_s, float* __restrict__ a_d, int N)
{
    int t = blockIdx.x * 256 + threadIdx.x;
    if (t >= N * 8) return;
    int n = t >> 3, hh = t & 7;
    const ushortv8* hp = (const ushortv8*)(h + (size_t)n * 256 + hh * 32);
    const float*    ap = att_s + hh * 32;
    const float*    bp = att_d + hh * 32;
    float ss = 0.f, dd = 0.f;
    #pragma unroll
    for (int i = 0; i < 4; ++i) {
        ushortv8 hv = hp[i];
        #pragma unroll
        for (int q = 0; q < 8; ++q) {
            float f = bf2f(hv[q]);
            ss += f * ap[i*8 + q];
            dd += f * bp[i*8 + q];
        }
    }
    a_s[t] = ss; a_d[t] = dd;
}

// ---------------------------------------------------------------------------
// CSR scan kernels
// ---------------------------------------------------------------------------
__global__ __launch_bounds__(256) void scan_blk(
    const int* __restrict__ counts, int* __restrict__ incl, int* __restrict__ bsum, int N)
{
    __shared__ int wtot[4], wexc[4];
    int t = blockIdx.x * 256 + threadIdx.x;
    int lane = threadIdx.x & 63, wid = threadIdx.x >> 6;
    int v = (t < N) ? counts[t] : 0;
    int s = v;
    #pragma unroll
    for (int off = 1; off < 64; off <<= 1) {
        int u = __shfl_up(s, off);
        if (lane >= off) s += u;
    }
    if (lane == 63) wtot[wid] = s;
    __syncthreads();
    if (threadIdx.x == 0) {
        int r = 0;
        #pragma unroll
        for (int w = 0; w < 4; ++w) { wexc[w] = r; r += wtot[w]; }
    }
    __syncthreads();
    int out = s + wexc[wid];
    if (t < N) incl[t] = out;
    if (threadIdx.x == 255) bsum[blockIdx.x] = out;
}

__global__ __launch_bounds__(256) void scan_top(int* __restrict__ bsum, int nb)
{
    __shared__ int wtot[4], wexc[4];
    int tid = threadIdx.x;
    int lane = tid & 63, wid = tid >> 6;
    int v = (tid < nb) ? bsum[tid] : 0;
    int s = v;
    #pragma unroll
    for (int off = 1; off < 64; off <<= 1) {
        int u = __shfl_up(s, off);
        if (lane >= off) s += u;
    }
    if (lane == 63) wtot[wid] = s;
    __syncthreads();
    if (tid == 0) {
        int r = 0;
        #pragma unroll
        for (int w = 0; w < 4; ++w) { wexc[w] = r; r += wtot[w]; }
    }
    __syncthreads();
    if (tid < nb) bsum[tid] = s + wexc[wid] - v;
}

// rowptr write + edge fill in one kernel (fill computes rowptr locally).
__global__ void fill_kernel(const int* __restrict__ src, const int* __restrict__ dst,
                            const int* __restrict__ incl, const int* __restrict__ bsum,
                            int* __restrict__ rowptr, int* __restrict__ cursor,
                            int* __restrict__ esrc, int N, int E)
{
    int t = blockIdx.x * 256 + threadIdx.x;
    if (t < N) {
        rowptr[t + 1] = incl[t] + bsum[t >> 8];
        if (t == 0) rowptr[0] = 0;
    }
    if (t < E) {
        int d = dst[t];
        int rp = bsum[d >> 8] + ((d & 255) ? incl[d - 1] : 0);
        int pos = rp + atomicAdd(&cursor[d], 1);
        esrc[pos] = src[t];
    }
}

// ---------------------------------------------------------------------------
// Per-node GAT aggregation, no-max softmax (logits bounded; exp(e)/sum(exp(e))
// is rounding-equivalent to the max-subtracted reference). No cross-lane ops
// in the main loop: each lane computes p for its own head directly.
// One wave per node; lane owns 4 channels of head lane>>3.
// ---------------------------------------------------------------------------
template<int LAYER>
__global__ __launch_bounds__(256) void gat_agg(
    const unsigned short* __restrict__ h, const float* __restrict__ a_s,
    const float* __restrict__ a_d, const int* __restrict__ rowptr,
    const int* __restrict__ esrc, const float* __restrict__ bias,
    float* __restrict__ out, unsigned short* __restrict__ out_b, int N)
{
    int n = blockIdx.x * 4 + (threadIdx.x >> 6);
    if (n >= N) return;
    int lane = threadIdx.x & 63;
    int beg = rowptr[n];
    int deg = rowptr[n + 1] - beg;
    int h_mine = lane >> 3;

    if (deg == 0) {
        if (LAYER == 1) {
            ushort4 o;
            float c0 = bias[lane*4+0], c1 = bias[lane*4+1], c2 = bias[lane*4+2], c3 = bias[lane*4+3];
            o.x = f2bf(c0 > 0.f ? c0 : expf(c0) - 1.f);
            o.y = f2bf(c1 > 0.f ? c1 : expf(c1) - 1.f);
            o.z = f2bf(c2 > 0.f ? c2 : expf(c2) - 1.f);
            o.w = f2bf(c3 > 0.f ? c3 : expf(c3) - 1.f);
            *(ushort4*)(out_b + (size_t)n*256 + lane*4) = o;
        } else {
            if (lane < 8) {
                #pragma unroll
                for (int q = 0; q < 4; ++q)
                    out[(size_t)n*32 + lane*4 + q] = bias[lane*4 + q];
            }
        }
        return;
    }

    float adn = a_d[(size_t)n*8 + h_mine];
    float dsum = 0.f;
    float4 acc = make_float4(0.f, 0.f, 0.f, 0.f);

    int j0 = 0;
    // full 8-edge batches: no guards, 8 gathers in flight
    for (; j0 + 8 <= deg; j0 += 8) {
        int sj[8]; float p[8];
        #pragma unroll
        for (int j = 0; j < 8; ++j) sj[j] = esrc[beg + j0 + j];   // broadcast loads
        #pragma unroll
        for (int j = 0; j < 8; ++j) {
            float e = a_s[(size_t)sj[j]*8 + h_mine] + adn;
            e = (e > 0.f) ? e : NEG_SLOPE * e;
            p[j] = __expf(e);
            dsum += p[j];
        }
        #pragma unroll
        for (int j = 0; j < 8; ++j) {
            ushort4 hv = *(const ushort4*)(h + (size_t)sj[j]*256 + lane*4);
            acc.x += p[j]*bf2f(hv.x); acc.y += p[j]*bf2f(hv.y);
            acc.z += p[j]*bf2f(hv.z); acc.w += p[j]*bf2f(hv.w);
        }
    }
    // tail batch (wave-uniform guards)
    if (j0 < deg) {
        int m = deg - j0;
        int sj[8]; float p[8];
        #pragma unroll
        for (int j = 0; j < 8; ++j) {
            int idx = j < m ? j : m - 1;
            sj[j] = esrc[beg + j0 + idx];
        }
        #pragma unroll
        for (int j = 0; j < 8; ++j) {
            float e = a_s[(size_t)sj[j]*8 + h_mine] + adn;
            e = (e > 0.f) ? e : NEG_SLOPE * e;
            float pv = __expf(e);
            p[j] = (j < m) ? pv : 0.f;
            dsum += p[j];
        }
        #pragma unroll
        for (int j = 0; j < 8; ++j) {
            if (j < m) {       // uniform branch: skip padded 512B gathers
                ushort4 hv = *(const ushort4*)(h + (size_t)sj[j]*256 + lane*4);
                acc.x += p[j]*bf2f(hv.x); acc.y += p[j]*bf2f(hv.y);
                acc.z += p[j]*bf2f(hv.z); acc.w += p[j]*bf2f(hv.w);
            }
        }
    }

    float invd = 1.f / (dsum + 1e-16f);
    if (LAYER == 1) {
        float r[4] = {acc.x, acc.y, acc.z, acc.w};
        ushort4 o; unsigned short* op = (unsigned short*)&o;
        #pragma unroll
        for (int q = 0; q < 4; ++q) {
            float val = r[q] * invd + bias[lane*4 + q];
            op[q] = f2bf(val > 0.f ? val : expf(val) - 1.f);
        }
        *(ushort4*)(out_b + (size_t)n*256 + lane*4) = o;
    } else {
        acc.x *= invd; acc.y *= invd; acc.z *= invd; acc.w *= invd;
        #pragma unroll
        for (int m = 8; m <= 32; m <<= 1) {
            acc.x += __shfl_xor(acc.x, m);
            acc.y += __shfl_xor(acc.y, m);
            acc.z += __shfl_xor(acc.z, m);
            acc.w += __shfl_xor(acc.w, m);
        }
        if (lane < 8) {
            float r[4] = {acc.x, acc.y, acc.z, acc.w};
            #pragma unroll
            for (int q = 0; q < 4; ++q)
                out[(size_t)n*32 + lane*4 + q] = r[q] * 0.125f + bias[lane*4 + q];
        }
    }
}

// ---------------------------------------------------------------------------
extern "C" void kernel_launch(void* const* d_in, const int* in_sizes, int n_in,
                              void* d_out, int out_size, void* d_ws, size_t ws_size,
                              hipStream_t stream)
{
    const float* x   = (const float*)d_in[0];
    const int*   ei  = (const int*)  d_in[1];
    const float* W1  = (const float*)d_in[2];
    const float* as1 = (const float*)d_in[3];
    const float* ad1 = (const float*)d_in[4];
    const float* b1  = (const float*)d_in[5];
    const float* W2  = (const float*)d_in[6];
    const float* as2 = (const float*)d_in[7];
    const float* ad2 = (const float*)d_in[8];
    const float* b2  = (const float*)d_in[9];

    const int N = in_sizes[0] / 128;
    const int E = in_sizes[1] / 2;
    const int* srcp = ei;
    const int* dstp = ei + E;

    // ---- workspace layout ----
    char* ws = (char*)d_ws;
    unsigned short* hb    = (unsigned short*)ws;  ws += (size_t)N * 256 * 2;
    unsigned short* xb    = (unsigned short*)ws;  ws += (size_t)N * 128 * 2;
    unsigned short* out1b = (unsigned short*)ws;  ws += (size_t)N * 256 * 2;
    unsigned short* Wt1   = (unsigned short*)ws;  ws += 256 * 128 * 2;
    unsigned short* Wt2   = (unsigned short*)ws;  ws += 256 * 256 * 2;
    float*          a_s   = (float*)ws;           ws += (size_t)N * 8 * 4;
    float*          a_d   = (float*)ws;           ws += (size_t)N * 8 * 4;
    int*            counts= (int*)ws;             ws += (size_t)N * 4;
    int*            cursor= (int*)ws;             ws += (size_t)N * 4;
    int*            incl  = (int*)ws;             ws += (size_t)N * 4;
    int*            bsum  = (int*)ws;             ws += 256 * 4;
    int*            rowptr= (int*)ws;             ws += (size_t)(N + 1) * 4;
    int*            esrc  = (int*)ws;

    const int nb  = (N + 255) / 256;
    const int n4x = N * 32;                          // N*128/4

    hipMemsetAsync(counts, 0, (size_t)2 * N * sizeof(int), stream);

    // prep: cvt + W transposes + histogram
    {
        int tot = n4x + 32768 + 65536 + E;
        prep_kernel<<<(tot + 255) / 256, 256, 0, stream>>>(
            x, xb, W1, Wt1, W2, Wt2, dstp, counts, n4x, E);
    }
    scan_blk<<<nb, 256, 0, stream>>>(counts, incl, bsum, N);
    scan_top<<<1, 256, 0, stream>>>(bsum, nb);
    fill_kernel<<<(E + 255) / 256, 256, 0, stream>>>(srcp, dstp, incl, bsum,
                                                     rowptr, cursor, esrc, N, E);

    const int gridM = (N + 127) / 128;

    // ---- layer 1 ----
    gemm_mfma<<<dim3(gridM, 2), 256, 0, stream>>>(xb, Wt1, hb, N, 128);
    att_kernel<<<(N * 8 + 255) / 256, 256, 0, stream>>>(hb, as1, ad1, a_s, a_d, N);
    gat_agg<1><<<(N + 3) / 4, 256, 0, stream>>>(hb, a_s, a_d, rowptr, esrc, b1,
                                                nullptr, out1b, N);

    // ---- layer 2 ----
    gemm_mfma<<<dim3(gridM, 2), 256, 0, stream>>>(out1b, Wt2, hb, N, 256);
    att_kernel<<<(N * 8 + 255) / 256, 256, 0, stream>>>(hb, as2, ad2, a_s, a_d, N);
    gat_agg<2><<<(N + 3) / 4, 256, 0, stream>>>(hb, a_s, a_d, rowptr, esrc, b2,
                                                (float*)d_out, nullptr, N);
}

// Round 6
// 203.399 us; speedup vs baseline: 2.2939x; 1.0659x over previous
//
#include <hip/hip_runtime.h>
#include <math.h>

#define NEG_SLOPE 0.2f

typedef float f32x4 __attribute__((ext_vector_type(4)));
typedef short bf16x8 __attribute__((ext_vector_type(8)));
typedef unsigned short ushortv8 __attribute__((ext_vector_type(8)));

__device__ __forceinline__ unsigned short f2bf(float f) {
    union { float f; unsigned u; } uu; uu.f = f;
    unsigned r = uu.u + 0x7FFF + ((uu.u >> 16) & 1);   // RNE, no NaN inputs
    return (unsigned short)(r >> 16);
}
__device__ __forceinline__ float bf2f(unsigned short u) {
    union { unsigned u; float f; } x; x.u = ((unsigned)u) << 16; return x.f;
}

// ---------------------------------------------------------------------------
// prep: x->bf16 convert | W1 transpose | W2 transpose | dst histogram.
// (verbatim from round-4 passing kernel)
// ---------------------------------------------------------------------------
__global__ void prep_kernel(const float* __restrict__ x, unsigned short* __restrict__ xb,
                            const float* __restrict__ W1, unsigned short* __restrict__ Wt1,
                            const float* __restrict__ W2, unsigned short* __restrict__ Wt2,
                            const int* __restrict__ dst, int* __restrict__ counts,
                            int n4x, int E)
{
    int t = blockIdx.x * 256 + threadIdx.x;
    if (t < n4x) {
        float4 v = ((const float4*)x)[t];
        ushort4 o;
        o.x = f2bf(v.x); o.y = f2bf(v.y); o.z = f2bf(v.z); o.w = f2bf(v.w);
        ((ushort4*)xb)[t] = o;
        return;
    }
    int u = t - n4x;
    if (u < 32768) {                       // Wt1[256][128]
        int nn = u >> 7, k = u & 127;
        Wt1[u] = f2bf(W1[(size_t)k * 256 + nn]);
        return;
    }
    u -= 32768;
    if (u < 65536) {                       // Wt2[256][256]
        int nn = u >> 8, k = u & 255;
        Wt2[u] = f2bf(W2[(size_t)k * 256 + nn]);
        return;
    }
    u -= 65536;
    if (u < E) atomicAdd(&counts[dst[u]], 1);
}

// ---------------------------------------------------------------------------
// MFMA GEMM (verbatim from round-4 passing kernel)
// ---------------------------------------------------------------------------
__global__ __launch_bounds__(256) void gemm_mfma(
    const unsigned short* __restrict__ A,
    const unsigned short* __restrict__ Bt,
    unsigned short* __restrict__ C,
    int M, int K)
{
    __shared__ unsigned short As[128 * 64];
    __shared__ unsigned short Bs[128 * 64];
    const int tid  = threadIdx.x;
    const int lane = tid & 63;
    const int wave = tid >> 6;
    const int wr = wave >> 1, wc = wave & 1;
    const int row0 = blockIdx.x * 128;
    const int col0 = blockIdx.y * 128;

    f32x4 acc[4][4] = {};

    for (int k0 = 0; k0 < K; k0 += 64) {
        ushortv8 va[4], vb[4];
        #pragma unroll
        for (int i = 0; i < 4; ++i) {
            int c  = i * 256 + tid;
            int r  = c >> 3, cc = c & 7;
            int ga = row0 + r; if (ga >= M) ga = M - 1;
            va[i] = *(const ushortv8*)(A  + (size_t)ga * K + k0 + cc * 8);
            vb[i] = *(const ushortv8*)(Bt + (size_t)(col0 + r) * K + k0 + cc * 8);
        }
        __syncthreads();
        #pragma unroll
        for (int i = 0; i < 4; ++i) {
            int c  = i * 256 + tid;
            int r  = c >> 3, cc = c & 7;
            int sl = cc ^ (r & 7);
            *(ushortv8*)(As + r * 64 + sl * 8) = va[i];
            *(ushortv8*)(Bs + r * 64 + sl * 8) = vb[i];
        }
        __syncthreads();

        #pragma unroll
        for (int kk = 0; kk < 2; ++kk) {
            const int kbyte = kk * 64 + ((lane >> 4) << 4);
            bf16x8 af[4], bfr[4];
            #pragma unroll
            for (int m = 0; m < 4; ++m) {
                int r = wr * 64 + m * 16 + (lane & 15);
                af[m] = *(const bf16x8*)((const char*)As + r * 128 + (kbyte ^ ((r & 7) << 4)));
            }
            #pragma unroll
            for (int n = 0; n < 4; ++n) {
                int r = wc * 64 + n * 16 + (lane & 15);
                bfr[n] = *(const bf16x8*)((const char*)Bs + r * 128 + (kbyte ^ ((r & 7) << 4)));
            }
            #pragma unroll
            for (int m = 0; m < 4; ++m)
                #pragma unroll
                for (int n = 0; n < 4; ++n)
                    acc[m][n] = __builtin_amdgcn_mfma_f32_16x16x32_bf16(
                        af[m], bfr[n], acc[m][n], 0, 0, 0);
        }
        __syncthreads();
    }

    #pragma unroll
    for (int m = 0; m < 4; ++m) {
        int rbase = row0 + wr * 64 + m * 16 + ((lane >> 4) << 2);
        #pragma unroll
        for (int j = 0; j < 4; ++j) {
            int grow = rbase + j;
            if (grow < M) {
                #pragma unroll
                for (int n = 0; n < 4; ++n)
                    C[(size_t)grow * 256 + col0 + wc * 64 + n * 16 + (lane & 15)] =
                        f2bf(acc[m][n][j]);
            }
        }
    }
}

// ---------------------------------------------------------------------------
// Attention logits from bf16 h. (verbatim from round-4 passing kernel)
// ---------------------------------------------------------------------------
__global__ void att_kernel(const unsigned short* __restrict__ h,
                           const float* __restrict__ att_s,
                           const float* __restrict__ att_d,
                           float* __restrict__ a_s, float* __restrict__ a_d, int N)
{
    int t = blockIdx.x * 256 + threadIdx.x;
    if (t >= N * 8) return;
    int n = t >> 3, hh = t & 7;
    const ushortv8* hp = (const ushortv8*)(h + (size_t)n * 256 + hh * 32);
    const float*    ap = att_s + hh * 32;
    const float*    bp = att_d + hh * 32;
    float ss = 0.f, dd = 0.f;
    #pragma unroll
    for (int i = 0; i < 4; ++i) {
        ushortv8 hv = hp[i];
        #pragma unroll
        for (int q = 0; q < 8; ++q) {
            float f = bf2f(hv[q]);
            ss += f * ap[i*8 + q];
            dd += f * bp[i*8 + q];
        }
    }
    a_s[t] = ss; a_d[t] = dd;
}

// ---------------------------------------------------------------------------
// CSR scan kernels (verbatim from round-4 passing kernel)
// ---------------------------------------------------------------------------
__global__ __launch_bounds__(256) void scan_blk(
    const int* __restrict__ counts, int* __restrict__ incl, int* __restrict__ bsum, int N)
{
    __shared__ int wtot[4], wexc[4];
    int t = blockIdx.x * 256 + threadIdx.x;
    int lane = threadIdx.x & 63, wid = threadIdx.x >> 6;
    int v = (t < N) ? counts[t] : 0;
    int s = v;
    #pragma unroll
    for (int off = 1; off < 64; off <<= 1) {
        int u = __shfl_up(s, off);
        if (lane >= off) s += u;
    }
    if (lane == 63) wtot[wid] = s;
    __syncthreads();
    if (threadIdx.x == 0) {
        int r = 0;
        #pragma unroll
        for (int w = 0; w < 4; ++w) { wexc[w] = r; r += wtot[w]; }
    }
    __syncthreads();
    int out = s + wexc[wid];
    if (t < N) incl[t] = out;
    if (threadIdx.x == 255) bsum[blockIdx.x] = out;
}

__global__ __launch_bounds__(256) void scan_top(int* __restrict__ bsum, int nb)
{
    __shared__ int wtot[4], wexc[4];
    int tid = threadIdx.x;
    int lane = tid & 63, wid = tid >> 6;
    int v = (tid < nb) ? bsum[tid] : 0;
    int s = v;
    #pragma unroll
    for (int off = 1; off < 64; off <<= 1) {
        int u = __shfl_up(s, off);
        if (lane >= off) s += u;
    }
    if (lane == 63) wtot[wid] = s;
    __syncthreads();
    if (tid == 0) {
        int r = 0;
        #pragma unroll
        for (int w = 0; w < 4; ++w) { wexc[w] = r; r += wtot[w]; }
    }
    __syncthreads();
    if (tid < nb) bsum[tid] = s + wexc[wid] - v;
}

__global__ void fill_kernel(const int* __restrict__ src, const int* __restrict__ dst,
                            const int* __restrict__ incl, const int* __restrict__ bsum,
                            int* __restrict__ rowptr, int* __restrict__ cursor,
                            int* __restrict__ esrc, int N, int E)
{
    int t = blockIdx.x * 256 + threadIdx.x;
    if (t < N) {
        rowptr[t + 1] = incl[t] + bsum[t >> 8];
        if (t == 0) rowptr[0] = 0;
    }
    if (t < E) {
        int d = dst[t];
        int rp = bsum[d >> 8] + ((d & 255) ? incl[d - 1] : 0);
        int pos = rp + atomicAdd(&cursor[d], 1);
        esrc[pos] = src[t];
    }
}

// ---------------------------------------------------------------------------
// Per-node GAT aggregation — NEW lane layout (the single change this round).
// One wave per node (4/block). half=lane>>5 handles every other edge;
// sl=lane&31 owns channels sl*8..sl*8+7 (one 16B ushortv8 gather covers a
// 512B h-row across 32 lanes -> 2 edges per gather instruction).
// head=sl>>2 (channel range sl*8..sl*8+7 never crosses a 32-boundary).
// No-max softmax; half-combine via single shfl_xor(32).
// ---------------------------------------------------------------------------
template<int LAYER>
__global__ __launch_bounds__(256) void gat_agg(
    const unsigned short* __restrict__ h, const float* __restrict__ a_s,
    const float* __restrict__ a_d, const int* __restrict__ rowptr,
    const int* __restrict__ esrc, const float* __restrict__ bias,
    float* __restrict__ out, unsigned short* __restrict__ out_b, int N)
{
    int n = blockIdx.x * 4 + (threadIdx.x >> 6);
    if (n >= N) return;
    const int lane = threadIdx.x & 63;
    const int half = lane >> 5;
    const int sl   = lane & 31;
    const int head = sl >> 2;
    int beg = rowptr[n];
    int deg = rowptr[n + 1] - beg;

    if (deg == 0) {
        if (LAYER == 1) {
            if (half == 0) {
                ushortv8 o;
                #pragma unroll
                for (int q = 0; q < 8; ++q) {
                    float b = bias[sl*8 + q];
                    o[q] = f2bf(b > 0.f ? b : expf(b) - 1.f);
                }
                *(ushortv8*)(out_b + (size_t)n*256 + sl*8) = o;
            }
        } else {
            if (lane < 4) {
                #pragma unroll
                for (int q = 0; q < 8; ++q)
                    out[(size_t)n*32 + lane*8 + q] = bias[lane*8 + q];
            }
        }
        return;
    }

    float adn = a_d[(size_t)n*8 + head];
    float dsum = 0.f;
    float acc[8] = {0.f,0.f,0.f,0.f,0.f,0.f,0.f,0.f};

    int j0 = 0;
    for (; j0 + 8 <= deg; j0 += 8) {
        // hoist the 4 pair-index loads ahead of the dependent chains
        int s0 = esrc[beg + j0 + 0 + half];
        int s1 = esrc[beg + j0 + 2 + half];
        int s2 = esrc[beg + j0 + 4 + half];
        int s3 = esrc[beg + j0 + 6 + half];
        int sv[4] = {s0, s1, s2, s3};
        #pragma unroll
        for (int k = 0; k < 4; ++k) {
            int s = sv[k];
            float e = a_s[(size_t)s*8 + head] + adn;
            e = (e > 0.f) ? e : NEG_SLOPE * e;
            float p = __expf(e);
            dsum += p;
            ushortv8 hv = *(const ushortv8*)(h + (size_t)s*256 + sl*8);
            #pragma unroll
            for (int q = 0; q < 8; ++q) acc[q] += p * bf2f(hv[q]);
        }
    }
    for (; j0 + 2 <= deg; j0 += 2) {
        int s = esrc[beg + j0 + half];
        float e = a_s[(size_t)s*8 + head] + adn;
        e = (e > 0.f) ? e : NEG_SLOPE * e;
        float p = __expf(e);
        dsum += p;
        ushortv8 hv = *(const ushortv8*)(h + (size_t)s*256 + sl*8);
        #pragma unroll
        for (int q = 0; q < 8; ++q) acc[q] += p * bf2f(hv[q]);
    }
    if (j0 < deg) {                      // single leftover edge (half 0 only)
        int s = esrc[beg + j0];
        if (half == 0) {
            float e = a_s[(size_t)s*8 + head] + adn;
            e = (e > 0.f) ? e : NEG_SLOPE * e;
            float p = __expf(e);
            dsum += p;
            ushortv8 hv = *(const ushortv8*)(h + (size_t)s*256 + sl*8);
            #pragma unroll
            for (int q = 0; q < 8; ++q) acc[q] += p * bf2f(hv[q]);
        }
    }

    // combine the two halves
    dsum += __shfl_xor(dsum, 32);
    #pragma unroll
    for (int q = 0; q < 8; ++q) acc[q] += __shfl_xor(acc[q], 32);
    float invd = 1.f / (dsum + 1e-16f);

    if (LAYER == 1) {
        if (half == 0) {
            ushortv8 o;
            #pragma unroll
            for (int q = 0; q < 8; ++q) {
                float val = acc[q] * invd + bias[sl*8 + q];
                o[q] = f2bf(val > 0.f ? val : expf(val) - 1.f);
            }
            *(ushortv8*)(out_b + (size_t)n*256 + sl*8) = o;
        }
    } else {
        #pragma unroll
        for (int q = 0; q < 8; ++q) acc[q] *= invd;
        // mean across heads: heads live on lane bits 2..4
        #pragma unroll
        for (int m = 4; m <= 16; m <<= 1)
            #pragma unroll
            for (int q = 0; q < 8; ++q) acc[q] += __shfl_xor(acc[q], m);
        if (lane < 4) {
            float4 lo = make_float4(acc[0]*0.125f + bias[lane*8+0],
                                    acc[1]*0.125f + bias[lane*8+1],
                                    acc[2]*0.125f + bias[lane*8+2],
                                    acc[3]*0.125f + bias[lane*8+3]);
            float4 hi = make_float4(acc[4]*0.125f + bias[lane*8+4],
                                    acc[5]*0.125f + bias[lane*8+5],
                                    acc[6]*0.125f + bias[lane*8+6],
                                    acc[7]*0.125f + bias[lane*8+7]);
            *(float4*)(out + (size_t)n*32 + lane*8)     = lo;
            *(float4*)(out + (size_t)n*32 + lane*8 + 4) = hi;
        }
    }
}

// ---------------------------------------------------------------------------
extern "C" void kernel_launch(void* const* d_in, const int* in_sizes, int n_in,
                              void* d_out, int out_size, void* d_ws, size_t ws_size,
                              hipStream_t stream)
{
    const float* x   = (const float*)d_in[0];
    const int*   ei  = (const int*)  d_in[1];
    const float* W1  = (const float*)d_in[2];
    const float* as1 = (const float*)d_in[3];
    const float* ad1 = (const float*)d_in[4];
    const float* b1  = (const float*)d_in[5];
    const float* W2  = (const float*)d_in[6];
    const float* as2 = (const float*)d_in[7];
    const float* ad2 = (const float*)d_in[8];
    const float* b2  = (const float*)d_in[9];

    const int N = in_sizes[0] / 128;
    const int E = in_sizes[1] / 2;
    const int* srcp = ei;
    const int* dstp = ei + E;

    // ---- workspace layout ----
    char* ws = (char*)d_ws;
    unsigned short* hb    = (unsigned short*)ws;  ws += (size_t)N * 256 * 2;
    unsigned short* xb    = (unsigned short*)ws;  ws += (size_t)N * 128 * 2;
    unsigned short* out1b = (unsigned short*)ws;  ws += (size_t)N * 256 * 2;
    unsigned short* Wt1   = (unsigned short*)ws;  ws += 256 * 128 * 2;
    unsigned short* Wt2   = (unsigned short*)ws;  ws += 256 * 256 * 2;
    float*          a_s   = (float*)ws;           ws += (size_t)N * 8 * 4;
    float*          a_d   = (float*)ws;           ws += (size_t)N * 8 * 4;
    int*            counts= (int*)ws;             ws += (size_t)N * 4;
    int*            cursor= (int*)ws;             ws += (size_t)N * 4;
    int*            incl  = (int*)ws;             ws += (size_t)N * 4;
    int*            bsum  = (int*)ws;             ws += 256 * 4;
    int*            rowptr= (int*)ws;             ws += (size_t)(N + 1) * 4;
    int*            esrc  = (int*)ws;

    const int nb  = (N + 255) / 256;
    const int n4x = N * 32;                          // N*128/4

    hipMemsetAsync(counts, 0, (size_t)2 * N * sizeof(int), stream);

    {
        int tot = n4x + 32768 + 65536 + E;
        prep_kernel<<<(tot + 255) / 256, 256, 0, stream>>>(
            x, xb, W1, Wt1, W2, Wt2, dstp, counts, n4x, E);
    }
    scan_blk<<<nb, 256, 0, stream>>>(counts, incl, bsum, N);
    scan_top<<<1, 256, 0, stream>>>(bsum, nb);
    fill_kernel<<<(E + 255) / 256, 256, 0, stream>>>(srcp, dstp, incl, bsum,
                                                     rowptr, cursor, esrc, N, E);

    const int gridM = (N + 127) / 128;

    // ---- layer 1 ----
    gemm_mfma<<<dim3(gridM, 2), 256, 0, stream>>>(xb, Wt1, hb, N, 128);
    att_kernel<<<(N * 8 + 255) / 256, 256, 0, stream>>>(hb, as1, ad1, a_s, a_d, N);
    gat_agg<1><<<(N + 3) / 4, 256, 0, stream>>>(hb, a_s, a_d, rowptr, esrc, b1,
                                                nullptr, out1b, N);

    // ---- layer 2 ----
    gemm_mfma<<<dim3(gridM, 2), 256, 0, stream>>>(out1b, Wt2, hb, N, 256);
    att_kernel<<<(N * 8 + 255) / 256, 256, 0, stream>>>(hb, as2, ad2, a_s, a_d, N);
    gat_agg<2><<<(N + 3) / 4, 256, 0, stream>>>(hb, a_s, a_d, rowptr, esrc, b2,
                                                (float*)d_out, nullptr, N);
}